// Round 10
// baseline (155.502 us; speedup 1.0000x reference)
//
#include <hip/hip_runtime.h>
#include <hip/hip_bf16.h>

// Problem constants (AFTLocalAutoregressive): T=2048, B=2, D=512, S=32
#define TT 2048
#define BB 2
#define DD 512
#define BD (BB*DD)        // 1024 columns (b,d flattened)
#define SS 32
#define MR (TT*BB)        // 4096 GEMM rows; m = 2t + b
#define NE (TT*BB*DD)     // 2097152 elements per (T,B,D) tensor
#define CH 32             // t-chunk size for scan/window (== one 64-row m-tile)

typedef __bf16 bf16x8 __attribute__((ext_vector_type(8)));
typedef float f32x4 __attribute__((ext_vector_type(4)));
typedef float f32x2 __attribute__((ext_vector_type(2)));

__device__ __forceinline__ void async_copy16(void* lds, const void* gptr) {
    __builtin_amdgcn_global_load_lds(
        (const __attribute__((address_space(1))) void*)gptr,
        (__attribute__((address_space(3))) void*)lds,
        16, 0, 0);
}

#define MFMA16(a,b,c) __builtin_amdgcn_mfma_f32_16x16x32_bf16((a),(b),(c),0,0,0)

// Read 8 consecutive fp32 from LDS (two b128) and convert to a bf16x8 frag.
__device__ __forceinline__ bf16x8 ldcvt(const char* p) {
    f32x4 x = *(const f32x4*)p;
    f32x4 y = *(const f32x4*)(p + 16);
    union { __hip_bfloat16 h[8]; bf16x8 v; } u;
    u.h[0] = __float2bfloat16(x[0]); u.h[1] = __float2bfloat16(x[1]);
    u.h[2] = __float2bfloat16(x[2]); u.h[3] = __float2bfloat16(x[3]);
    u.h[4] = __float2bfloat16(y[0]); u.h[5] = __float2bfloat16(y[1]);
    u.h[6] = __float2bfloat16(y[2]); u.h[7] = __float2bfloat16(y[3]);
    return u.v;
}

// ---------------------------------------------------------------------------
// cast_all ELIMINATED (r10): fp32 operands staged directly via global_load_lds
// (no VGPR round-trip -> not r6's reg-staging trap); fp32->bf16 conversion
// happens between LDS read and MFMA (ldcvt).  Bit-identical numerics to the
// cast_all path (same RNE cast feeding the same MFMA).
// fp32 LDS layout per 8KB operand: off = kq*2048 + row*32 + half*16.
// Staging lane-map (linear dest = base + lane*16): copy c via wave wv, lane l
// covers (kq = c*2 + (wv>>1), row = (wv&1)*32 + (l>>1), half = l&1); the
// global source address mirrors that mapping.
//
// z=0: qf = sigmoid(query@Wq^T + bq); 3-deep pipeline, counted vmcnt(4)
//      (4 copies/tile), LDS 48KB.
// z=1: k,v fused; 4 fp32 operands = 32KB/buffer -> 2-buffer @64KB, m97-style
//      vmcnt(0) drain per K-step.  Epilogue (ekn/part) unchanged from r9.
// XCD-aware tile remap (r9) kept: flat = bx + 8*by; mt = flat&63; nt = flat>>6.
// ---------------------------------------------------------------------------
__global__ __launch_bounds__(256) void gemm_qkv(
    const float* __restrict__ query, const float* __restrict__ key,
    const float* __restrict__ value,
    const float* __restrict__ Wq, const float* __restrict__ Wk,
    const float* __restrict__ Wv,
    const float* __restrict__ bq, const float* __restrict__ bk,
    const float* __restrict__ bv,
    float* __restrict__ qout, float* __restrict__ ekn,
    float* __restrict__ part)
{
    __shared__ char smem[65536];
    const int tid = threadIdx.x;
    const int lane = tid & 63;
    const int wv = tid >> 6;
    const int wave_m = wv >> 1, wave_n = wv & 1;
    const int flat = blockIdx.x + 8 * blockIdx.y;   // 0..511
    const int mt = flat & 63, nt = flat >> 6;       // XCD = flat%8 = mt%8
    const int m0 = mt * 64, n0 = nt * 64;
    const int kq = lane >> 4, rr = lane & 15;
    // staging lane-map
    const int srow  = ((wv & 1) << 5) + (lane >> 1);   // 0..63
    const int skq0  = (wv >> 1);                       // kq for c=0; c=1 -> +2
    const int shalf = (lane & 1) * 4;                  // float offset

    if (blockIdx.z == 0) {
        f32x4 acc[2][2] = {};
        const float* a0s = query + (size_t)(m0 + srow) * DD + skq0 * 8 + shalf;
        const float* a1s = a0s + 16;                   // c=1: kq+2 octets
        const float* w0s = Wq    + (size_t)(n0 + srow) * DD + skq0 * 8 + shalf;
        const float* w1s = w0s + 16;
        // buffer b at smem + b*16384: A fp32 8KB @0, W fp32 8KB @8192
#define STQ(b, t) { \
        async_copy16(smem + (b)*16384 +        0 + wv*1024, a0s + (t)*32); \
        async_copy16(smem + (b)*16384 +     4096 + wv*1024, a1s + (t)*32); \
        async_copy16(smem + (b)*16384 + 8192 + 0 + wv*1024, w0s + (t)*32); \
        async_copy16(smem + (b)*16384 + 8192+4096 + wv*1024, w1s + (t)*32); }
        STQ(0, 0); STQ(1, 1);
        asm volatile("s_waitcnt vmcnt(4)" ::: "memory");   // tile 0 landed
        __builtin_amdgcn_s_barrier();
        #pragma unroll
        for (int it = 0; it < 16; ++it) {
            if (it + 2 < 16) STQ((it + 2) % 3, it + 2);
            const char* cb = smem + (it % 3) * 16384;
            bf16x8 a0 = ldcvt(cb +        kq*2048 + (wave_m*32 +  0 + rr)*32);
            bf16x8 a1 = ldcvt(cb +        kq*2048 + (wave_m*32 + 16 + rr)*32);
            bf16x8 w0 = ldcvt(cb + 8192 + kq*2048 + (wave_n*32 +  0 + rr)*32);
            bf16x8 w1 = ldcvt(cb + 8192 + kq*2048 + (wave_n*32 + 16 + rr)*32);
            acc[0][0] = MFMA16(a0, w0, acc[0][0]);
            acc[0][1] = MFMA16(a0, w1, acc[0][1]);
            acc[1][0] = MFMA16(a1, w0, acc[1][0]);
            acc[1][1] = MFMA16(a1, w1, acc[1][1]);
            if (it < 15) {
                if (it < 14) asm volatile("s_waitcnt vmcnt(4) lgkmcnt(0)" ::: "memory");
                else         asm volatile("s_waitcnt vmcnt(0) lgkmcnt(0)" ::: "memory");
                __builtin_amdgcn_s_barrier();
            }
        }
#undef STQ
        #pragma unroll
        for (int ms = 0; ms < 2; ++ms)
            #pragma unroll
            for (int ns = 0; ns < 2; ++ns) {
                int n = n0 + wave_n*32 + ns*16 + rr;
                float bn = bq[n];
                #pragma unroll
                for (int r = 0; r < 4; ++r) {
                    int m = m0 + wave_m*32 + ms*16 + kq*4 + r;
                    float x = acc[ms][ns][r] + bn;
                    qout[(size_t)m * DD + n] = 1.f / (1.f + expf(-x));  // sigmoid folded
                }
            }
    } else {
        f32x4 acck[2][2] = {}, accv[2][2] = {};
        const float* ak0s = key   + (size_t)(m0 + srow) * DD + skq0 * 8 + shalf;
        const float* ak1s = ak0s + 16;
        const float* wk0s = Wk    + (size_t)(n0 + srow) * DD + skq0 * 8 + shalf;
        const float* wk1s = wk0s + 16;
        const float* av0s = value + (size_t)(m0 + srow) * DD + skq0 * 8 + shalf;
        const float* av1s = av0s + 16;
        const float* wv0s = Wv    + (size_t)(n0 + srow) * DD + skq0 * 8 + shalf;
        const float* wv1s = wv0s + 16;
        // buffer b at smem + b*32768: AK@0, WK@8192, AV@16384, WV@24576 (8KB each)
#define ST1(b, t) { \
        async_copy16(smem + (b)*32768 +         0 + wv*1024, ak0s + (t)*32); \
        async_copy16(smem + (b)*32768 +      4096 + wv*1024, ak1s + (t)*32); \
        async_copy16(smem + (b)*32768 +  8192 + 0 + wv*1024, wk0s + (t)*32); \
        async_copy16(smem + (b)*32768 +  8192+4096 + wv*1024, wk1s + (t)*32); \
        async_copy16(smem + (b)*32768 + 16384 + 0 + wv*1024, av0s + (t)*32); \
        async_copy16(smem + (b)*32768 + 16384+4096 + wv*1024, av1s + (t)*32); \
        async_copy16(smem + (b)*32768 + 24576 + 0 + wv*1024, wv0s + (t)*32); \
        async_copy16(smem + (b)*32768 + 24576+4096 + wv*1024, wv1s + (t)*32); }
        ST1(0, 0);
        asm volatile("s_waitcnt vmcnt(0)" ::: "memory");
        __builtin_amdgcn_s_barrier();
        #pragma unroll
        for (int it = 0; it < 16; ++it) {
            if (it + 1 < 16) ST1((it + 1) & 1, it + 1);
            const char* cb = smem + (it & 1) * 32768;
            bf16x8 ak0 = ldcvt(cb +         kq*2048 + (wave_m*32 +  0 + rr)*32);
            bf16x8 ak1 = ldcvt(cb +         kq*2048 + (wave_m*32 + 16 + rr)*32);
            bf16x8 bk0 = ldcvt(cb +  8192 + kq*2048 + (wave_n*32 +  0 + rr)*32);
            bf16x8 bk1 = ldcvt(cb +  8192 + kq*2048 + (wave_n*32 + 16 + rr)*32);
            bf16x8 av0 = ldcvt(cb + 16384 + kq*2048 + (wave_m*32 +  0 + rr)*32);
            bf16x8 av1 = ldcvt(cb + 16384 + kq*2048 + (wave_m*32 + 16 + rr)*32);
            bf16x8 bv0 = ldcvt(cb + 24576 + kq*2048 + (wave_n*32 +  0 + rr)*32);
            bf16x8 bv1 = ldcvt(cb + 24576 + kq*2048 + (wave_n*32 + 16 + rr)*32);
            acck[0][0] = MFMA16(ak0, bk0, acck[0][0]);
            acck[0][1] = MFMA16(ak0, bk1, acck[0][1]);
            acck[1][0] = MFMA16(ak1, bk0, acck[1][0]);
            acck[1][1] = MFMA16(ak1, bk1, acck[1][1]);
            accv[0][0] = MFMA16(av0, bv0, accv[0][0]);
            accv[0][1] = MFMA16(av0, bv1, accv[0][1]);
            accv[1][0] = MFMA16(av1, bv0, accv[1][0]);
            accv[1][1] = MFMA16(av1, bv1, accv[1][1]);
            if (it < 15) {
                asm volatile("s_waitcnt vmcnt(0) lgkmcnt(0)" ::: "memory");
                __builtin_amdgcn_s_barrier();
            }
        }
#undef ST1
        // epilogue: interleaved ekn stores + per-chunk column sums (b = r&1)
        float sd[2][2] = {{0.f,0.f},{0.f,0.f}};   // [ns][parity]
        float sn[2][2] = {{0.f,0.f},{0.f,0.f}};
        #pragma unroll
        for (int ms = 0; ms < 2; ++ms)
            #pragma unroll
            for (int ns = 0; ns < 2; ++ns) {
                int n = n0 + wave_n*32 + ns*16 + rr;
                float bkn = bk[n], bvn = bv[n];
                #pragma unroll
                for (int r = 0; r < 4; ++r) {
                    int m = m0 + wave_m*32 + ms*16 + kq*4 + r;
                    float e  = expf(acck[ms][ns][r] + bkn);
                    float nv = e * (accv[ms][ns][r] + bvn);
                    float2 st; st.x = e; st.y = nv;
                    *(float2*)&ekn[((size_t)m * DD + n) * 2] = st;
                    sd[ns][r & 1] += e;
                    sn[ns][r & 1] += nv;
                }
            }
        #pragma unroll
        for (int ns = 0; ns < 2; ++ns)
            #pragma unroll
            for (int par = 0; par < 2; ++par) {
                sd[ns][par] += __shfl_xor(sd[ns][par], 16, 64);
                sd[ns][par] += __shfl_xor(sd[ns][par], 32, 64);
                sn[ns][par] += __shfl_xor(sn[ns][par], 16, 64);
                sn[ns][par] += __shfl_xor(sn[ns][par], 32, 64);
            }
        __syncthreads();                       // smem free for reuse
        float* red = (float*)smem;             // red[which(4)][wave_m(2)][64]
        if (lane < 16) {
            #pragma unroll
            for (int ns = 0; ns < 2; ++ns) {
                int c2 = wave_n*32 + ns*16 + rr;
                red[(0*2 + wave_m)*64 + c2] = sd[ns][0];
                red[(1*2 + wave_m)*64 + c2] = sd[ns][1];
                red[(2*2 + wave_m)*64 + c2] = sn[ns][0];
                red[(3*2 + wave_m)*64 + c2] = sn[ns][1];
            }
        }
        __syncthreads();
        {
            int which = tid >> 6;              // 0: d,b0  1: d,b1  2: n,b0  3: n,b1
            int c2 = tid & 63;
            float s = red[(which*2 + 0)*64 + c2] + red[(which*2 + 1)*64 + c2];
            int b = which & 1;
            int sel = which >> 1;              // 0 = den, 1 = num
            part[((size_t)mt * BD + b*512 + n0 + c2) * 2 + sel] = s;
        }
    }
}

// ---------------------------------------------------------------------------
// fused_window: unchanged from r9 (LDS-staged E-tile, inline chunk-prefix,
// static-index register ring — rule #20 fix verified r8).  qf = sigmoid(q).
// ---------------------------------------------------------------------------
__global__ __launch_bounds__(256, 3) void fused_window(
    const float* __restrict__ qf, const float* __restrict__ ekn,
    const float* __restrict__ part, const float* __restrict__ pb,
    __hip_bfloat16* __restrict__ yb)
{
    __shared__ float Et[64 * 64 * 2];     // 32 KB: [u][c] f32x2
    __shared__ float wl[CH][SS];          // 4 KB
    __shared__ float red[4 * 64 * 2];     // 2 KB
    const int tid = threadIdx.x;
    const int chunk = blockIdx.y;
    const int t0 = chunk * CH;
    const int col0 = blockIdx.x * 64;
    const int c = tid & 63;
    const int sg = tid >> 6;              // wave = s-group
    const int s0 = sg * 8;

    // Stage E tile: thread covers 16B (2 cols) of row u = (tid>>5) + j*8
    {
        const int cp = tid & 31;          // col-pair
        #pragma unroll
        for (int j = 0; j < 8; ++j) {
            int u = (tid >> 5) + j * 8;
            int t = t0 - 32 + u;
            if (t >= 0) {                 // wave-uniform (chunk==0: skips j<4)
                const void* g = (const void*)(ekn + ((size_t)t * BD + col0 + cp * 2) * 2);
                async_copy16((char*)Et + (tid >> 6) * 1024 + j * 4096, g);
            }
        }
        if (chunk == 0) {                 // zero rows 0..31 (t<0)
            f32x4 z = {0.f, 0.f, 0.f, 0.f};
            #pragma unroll
            for (int j = 0; j < 4; ++j)
                *(f32x4*)((char*)Et + tid * 16 + j * 4096) = z;
        }
    }

    // wl[t_local][j] = valid * exp(pb[t, t-31+j])
    #pragma unroll
    for (int i = 0; i < (CH * SS) / 256; ++i) {
        int idx = tid + i * 256;
        int tl = idx >> 5, jj = idx & 31;
        int t = t0 + tl;
        int u2 = t - (SS - 1) + jj;
        float w = 0.f;
        if (u2 >= 0) w = expf(pb[(size_t)t * TT + u2]);
        wl[tl][jj] = w;
    }

    // qv (sigmoid already applied) + inline chunk-prefix partial
    float qv[8];
    #pragma unroll
    for (int k = 0; k < 8; ++k)
        qv[k] = qf[(size_t)(t0 + s0 + k) * BD + col0 + c];
    f32x2 acc2 = {0.f, 0.f};
    #pragma unroll
    for (int j = 0; j < 16; ++j) {
        int p = sg + 4 * j;
        if (p < chunk)                    // wave-uniform predicate
            acc2 += *(const f32x2*)&part[((size_t)p * BD + col0 + c) * 2];
    }
    *(f32x2*)&red[(sg * 64 + c) * 2] = acc2;

    __syncthreads();                      // drains copies + wl + red

    f32x2 P = *(const f32x2*)&red[(0 * 64 + c) * 2];
    P += *(const f32x2*)&red[(1 * 64 + c) * 2];
    P += *(const f32x2*)&red[(2 * 64 + c) * 2];
    P += *(const f32x2*)&red[(3 * 64 + c) * 2];

    // Pull rows s0+1 .. s0+39 once into registers (ALL indices static)
    f32x2 ring[39];
    #pragma unroll
    for (int i = 0; i < 39; ++i)
        ring[i] = *(const f32x2*)&Et[((s0 + 1 + i) * 64 + c) * 2];

    // cs(s0) = P - sum_{u=s0+1}^{31} E[u]; wave-uniform branch keeps every
    // ring index compile-time constant (rule #20).
    f32x2 cs = P;
    if (sg == 0) {
        #pragma unroll
        for (int i = 0; i < 31; ++i) cs -= ring[i];
    } else if (sg == 1) {
        #pragma unroll
        for (int i = 0; i < 23; ++i) cs -= ring[i];
    } else if (sg == 2) {
        #pragma unroll
        for (int i = 0; i < 15; ++i) cs -= ring[i];
    } else {
        #pragma unroll
        for (int i = 0; i < 7; ++i) cs -= ring[i];
    }

    #pragma unroll
    for (int k = 0; k < 8; ++k) {
        int s = s0 + k;
        if (k > 0) cs += ring[k - 1];
        f32x2 acc = cs;
        #pragma unroll
        for (int j4 = 0; j4 < 8; ++j4) {
            float4 w4 = *(const float4*)&wl[s][j4 * 4];
            acc += w4.x * ring[k + j4*4 + 0];
            acc += w4.y * ring[k + j4*4 + 1];
            acc += w4.z * ring[k + j4*4 + 2];
            acc += w4.w * ring[k + j4*4 + 3];
        }
        yb[(size_t)(t0 + s) * BD + col0 + c] = __float2bfloat16(qv[k] * acc.y / acc.x);
    }
}

// ---------------------------------------------------------------------------
// out = yb@Wo^T + bo.  yb bf16 (1 copy/tile, bf16 layout), Wo staged fp32
// (2 copies/tile, fp32 layout + ldcvt).  3-deep pipeline, counted vmcnt(3).
// XCD-aware remap kept.
// ---------------------------------------------------------------------------
__global__ __launch_bounds__(256) void gemm_out(
    const __hip_bfloat16* __restrict__ yb, const float* __restrict__ Wo,
    const float* __restrict__ bo, float* __restrict__ out)
{
    __shared__ char smem[36864];          // 3 buffers of 12KB: A bf16 4KB @0, W fp32 8KB @4096
    const int tid = threadIdx.x;
    const int lane = tid & 63;
    const int wv = tid >> 6;
    const int wave_m = wv >> 1, wave_n = wv & 1;
    const int flat = blockIdx.x + 8 * blockIdx.y;   // 0..511
    const int mt = flat & 63, nt = flat >> 6;       // XCD = flat%8 = mt%8
    const int m0 = mt * 64, n0 = nt * 64;
    const int kq = lane >> 4, rr = lane & 15;
    const int srow  = ((wv & 1) << 5) + (lane >> 1);
    const int skq0  = (wv >> 1);
    const int shalf = (lane & 1) * 4;

    f32x4 acc[2][2] = {};
    const __hip_bfloat16* Arow = yb + (size_t)(m0 + lane) * DD + wv * 8;   // bf16 map (kq=wv,row=lane)
    const float* w0s = Wo + (size_t)(n0 + srow) * DD + skq0 * 8 + shalf;
    const float* w1s = w0s + 16;
#define STO(b, t) { \
    async_copy16(smem + (b)*12288 +           wv*1024, Arow + (t)*32); \
    async_copy16(smem + (b)*12288 + 4096 +    wv*1024, w0s + (t)*32); \
    async_copy16(smem + (b)*12288 + 4096+4096 + wv*1024, w1s + (t)*32); }
    STO(0, 0); STO(1, 1);
    asm volatile("s_waitcnt vmcnt(3)" ::: "memory");   // tile 0 landed
    __builtin_amdgcn_s_barrier();
    #pragma unroll
    for (int it = 0; it < 16; ++it) {
        if (it + 2 < 16) STO((it + 2) % 3, it + 2);
        const char* cb = smem + (it % 3) * 12288;
        bf16x8 a0 = *(const bf16x8*)(cb + kq*1024 + (wave_m*32 +  0 + rr)*16);
        bf16x8 a1 = *(const bf16x8*)(cb + kq*1024 + (wave_m*32 + 16 + rr)*16);
        bf16x8 w0 = ldcvt(cb + 4096 + kq*2048 + (wave_n*32 +  0 + rr)*32);
        bf16x8 w1 = ldcvt(cb + 4096 + kq*2048 + (wave_n*32 + 16 + rr)*32);
        acc[0][0] = MFMA16(a0, w0, acc[0][0]);
        acc[0][1] = MFMA16(a0, w1, acc[0][1]);
        acc[1][0] = MFMA16(a1, w0, acc[1][0]);
        acc[1][1] = MFMA16(a1, w1, acc[1][1]);
        if (it < 15) {
            if (it < 14) asm volatile("s_waitcnt vmcnt(3) lgkmcnt(0)" ::: "memory");
            else         asm volatile("s_waitcnt vmcnt(0) lgkmcnt(0)" ::: "memory");
            __builtin_amdgcn_s_barrier();
        }
    }
#undef STO
    #pragma unroll
    for (int ms = 0; ms < 2; ++ms)
        #pragma unroll
        for (int ns = 0; ns < 2; ++ns) {
            int n = n0 + wave_n*32 + ns*16 + rr;
            float bn = bo[n];
            #pragma unroll
            for (int r = 0; r < 4; ++r) {
                int m = m0 + wave_m*32 + ms*16 + kq*4 + r;
                out[(size_t)m * DD + n] = acc[ms][ns][r] + bn;
            }
        }
}

extern "C" void kernel_launch(void* const* d_in, const int* in_sizes, int n_in,
                              void* d_out, int out_size, void* d_ws, size_t ws_size,
                              hipStream_t stream) {
    const float* query = (const float*)d_in[0];
    const float* key   = (const float*)d_in[1];
    const float* value = (const float*)d_in[2];
    const float* Wq    = (const float*)d_in[3];
    const float* bq    = (const float*)d_in[4];
    const float* Wk    = (const float*)d_in[5];
    const float* bk    = (const float*)d_in[6];
    const float* Wv    = (const float*)d_in[7];
    const float* bv    = (const float*)d_in[8];
    const float* pb    = (const float*)d_in[9];
    const float* Wo    = (const float*)d_in[10];
    const float* bo    = (const float*)d_in[11];
    float* out = (float*)d_out;

    float* ws = (float*)d_ws;
    float* qf   = ws;                         // NE (sigmoid(q))
    float* ekn  = ws + (size_t)NE;            // 2*NE (interleaved {den,num})
    float* part = ws + (size_t)3 * NE;        // 2*64*1024 = 131072
    __hip_bfloat16* yb = (__hip_bfloat16*)(part + 131072);  // NE bf16

    gemm_qkv<<<dim3(DD / 64, MR / 64, 2), 256, 0, stream>>>(
        query, key, value, Wq, Wk, Wv, bq, bk, bv,
        qf, ekn, part);

    fused_window<<<dim3(BD / 64, TT / CH), 256, 0, stream>>>(
        qf, ekn, part, pb, yb);

    gemm_out<<<dim3(DD / 64, MR / 64), 256, 0, stream>>>(yb, Wo, bo, out);
}